// Round 1
// 735.902 us; speedup vs baseline: 1.0149x; 1.0149x over previous
//
#include <hip/hip_runtime.h>
#include <math.h>

#define DDIM 256
#define CHUNK 256      // nodes per block in fused kernel (was 512)
#define WCHUNK 64      // nodes per wave (was 128)
#define TM 64
#define TN 64
#define TK 32

// ---- Fused kernel: gate dot + w^p*exp + segment pooling, ONE pass over x --
// Block = 256 threads = 4 waves; each wave walks 64 consecutive (sorted)
// nodes in GROUPS OF 4 for ILP: 4 independent row loads in flight, 4
// independent 6-step butterfly reduce chains, then 4 exp+accumulates.
// Flush to pooled[] via atomicAdd only at segment boundaries.
__global__ __launch_bounds__(256) void k_fused(
    const float* __restrict__ x, const float* __restrict__ weights,
    const float* __restrict__ Wg, const float* __restrict__ bg,
    const float* __restrict__ p_, const int* __restrict__ index,
    float* __restrict__ pooled, float* __restrict__ denom, int N)
{
    __shared__ int   s_seg[CHUNK];
    __shared__ float s_wp[CHUNK];
    const int n0 = blockIdx.x * CHUNK;
    const float p = p_[0];
    {
        int jj = threadIdx.x;              // CHUNK == blockDim.x == 256
        int i = n0 + jj;
        if (i < N) {
            s_seg[jj] = index[i];
            s_wp[jj]  = powf(weights[i], p);
        } else {
            s_seg[jj] = -1;
        }
    }
    __syncthreads();

    const int lane = threadIdx.x & 63;
    const int wave = threadIdx.x >> 6;
    const float4 wg = ((const float4*)Wg)[lane];
    const float b = bg[0];
    const int j0 = wave * WCHUNK;
    const float4* x4 = (const float4*)x;

    float4 acc = make_float4(0.f, 0.f, 0.f, 0.f);
    float wsum = 0.f;
    int prev = -1;

    for (int j = j0; j < j0 + WCHUNK; j += 4) {
        if (n0 + j >= N) break;            // wave-uniform

        // 4 independent loads in flight (clamped addr, validity via s_seg)
        float4 xv[4];
        #pragma unroll
        for (int t = 0; t < 4; ++t) {
            int i = n0 + j + t;
            int ic = i < N ? i : N - 1;
            xv[t] = x4[(size_t)ic * (DDIM/4) + lane];
        }

        float d[4];
        #pragma unroll
        for (int t = 0; t < 4; ++t)
            d[t] = xv[t].x*wg.x + xv[t].y*wg.y + xv[t].z*wg.z + xv[t].w*wg.w;

        // 4 independent butterfly chains (overlapped ds latency)
        #pragma unroll
        for (int m = 32; m >= 1; m >>= 1) {
            #pragma unroll
            for (int t = 0; t < 4; ++t)
                d[t] += __shfl_xor(d[t], m, 64);
        }

        #pragma unroll
        for (int t = 0; t < 4; ++t) {
            int s = s_seg[j + t];
            if (s < 0) break;              // wave-uniform end-of-data
            if (s != prev) {               // wave-uniform (sorted index)
                if (prev >= 0) {
                    float* pp = &pooled[(size_t)prev * DDIM + lane * 4];
                    atomicAdd(pp + 0, acc.x); atomicAdd(pp + 1, acc.y);
                    atomicAdd(pp + 2, acc.z); atomicAdd(pp + 3, acc.w);
                    if (lane == 0) atomicAdd(&denom[prev], wsum);
                }
                acc = make_float4(0.f, 0.f, 0.f, 0.f);
                wsum = 0.f;
                prev = s;
            }
            float w = s_wp[j + t] * __expf(d[t] + b);
            acc.x += w * xv[t].x; acc.y += w * xv[t].y;
            acc.z += w * xv[t].z; acc.w += w * xv[t].w;
            wsum += w;
        }
    }
    if (prev >= 0) {
        float* pp = &pooled[(size_t)prev * DDIM + lane * 4];
        atomicAdd(pp + 0, acc.x); atomicAdd(pp + 1, acc.y);
        atomicAdd(pp + 2, acc.z); atomicAdd(pp + 3, acc.w);
        if (lane == 0) atomicAdd(&denom[prev], wsum);
    }
}

// ---- GEMM: out = (pooled @ Wm) * scale + bm * (denom*scale) ---------------
// scale_s = 1/(denom_s + 1e-10) applied in the epilogue (normalization is a
// per-row scalar, commutes with the linear map). 64x64 tile, 4x4 micro.
__global__ __launch_bounds__(256) void k_gemm(
    const float* __restrict__ pooled, const float* __restrict__ Wm,
    const float* __restrict__ bm, const float* __restrict__ denom,
    float* __restrict__ out, int S)
{
    __shared__ float At[TK][TM + 4];   // A transposed: At[k][r]
    __shared__ float Bs[TK][TN];
    const int tx = threadIdx.x & 15;
    const int ty = threadIdx.x >> 4;
    const int r0 = blockIdx.x * TM;
    const int c0 = blockIdx.y * TN;
    float acc[4][4] = {};

    for (int k0 = 0; k0 < DDIM; k0 += TK) {
        #pragma unroll
        for (int it = 0; it < 2; ++it) {
            int idx = threadIdx.x + it * 256;
            {   // stage A transposed: 64 rows x 32 k
                int r  = idx >> 3;
                int kq = (idx & 7) * 4;
                float4 a = make_float4(0.f, 0.f, 0.f, 0.f);
                if (r0 + r < S)
                    a = *(const float4*)&pooled[(size_t)(r0 + r) * DDIM + k0 + kq];
                At[kq + 0][r] = a.x; At[kq + 1][r] = a.y;
                At[kq + 2][r] = a.z; At[kq + 3][r] = a.w;
            }
            {   // stage B: 32 k x 64 cols
                int k  = idx >> 4;
                int cq = (idx & 15) * 4;
                *(float4*)&Bs[k][cq] =
                    *(const float4*)&Wm[(size_t)(k0 + k) * DDIM + c0 + cq];
            }
        }
        __syncthreads();
        #pragma unroll
        for (int k = 0; k < TK; ++k) {
            const float4 av = *(const float4*)&At[k][ty * 4];
            const float4 bv = *(const float4*)&Bs[k][tx * 4];
            float a4[4] = {av.x, av.y, av.z, av.w};
            float b4[4] = {bv.x, bv.y, bv.z, bv.w};
            #pragma unroll
            for (int i = 0; i < 4; ++i)
                #pragma unroll
                for (int j = 0; j < 4; ++j)
                    acc[i][j] += a4[i] * b4[j];
        }
        __syncthreads();
    }

    const float4 bmv = *(const float4*)&bm[c0 + tx * 4];
    #pragma unroll
    for (int i = 0; i < 4; ++i) {
        int row = r0 + ty * 4 + i;
        if (row >= S) continue;
        float dn = denom[row];
        float scale = 1.f / (dn + 1e-10f);
        float gs = dn * scale;
        float4 o;
        o.x = acc[i][0] * scale + gs * bmv.x;
        o.y = acc[i][1] * scale + gs * bmv.y;
        o.z = acc[i][2] * scale + gs * bmv.z;
        o.w = acc[i][3] * scale + gs * bmv.w;
        *(float4*)&out[(size_t)row * DDIM + c0 + tx * 4] = o;
    }
}

extern "C" void kernel_launch(void* const* d_in, const int* in_sizes, int n_in,
                              void* d_out, int out_size, void* d_ws, size_t ws_size,
                              hipStream_t stream) {
    const float* x       = (const float*)d_in[0];
    const float* weights = (const float*)d_in[1];
    const float* Wg      = (const float*)d_in[2];
    const float* bg      = (const float*)d_in[3];
    const float* Wm      = (const float*)d_in[4];
    const float* bm      = (const float*)d_in[5];
    const float* p       = (const float*)d_in[6];
    const int*   index   = (const int*)d_in[7];

    const int N = in_sizes[1];        // weights is (N,1)
    const int D = in_sizes[2];        // Wg is (D,1) -> 256
    const int S = out_size / D;
    float* out = (float*)d_out;

    float* denom  = (float*)d_ws;
    float* pooled = denom + S;

    // denom and pooled are contiguous: one fill instead of two
    hipMemsetAsync(denom, 0, (size_t)S * (D + 1) * sizeof(float), stream);

    k_fused<<<(N + CHUNK - 1) / CHUNK, 256, 0, stream>>>(
        x, weights, Wg, bg, p, index, pooled, denom, N);

    dim3 g2((S + TM - 1) / TM, D / TN);
    k_gemm<<<g2, 256, 0, stream>>>(pooled, Wm, bm, denom, out, S);
}